// Round 7
// baseline (509.605 us; speedup 1.0000x reference)
//
#include <hip/hip_runtime.h>
#include <hip/hip_bf16.h>

#define M_ROWS 16384
#define N_CODES 8192
#define DDIM    512
#define NCHUNK  256          // 32-code chunks
#define MARGIN  2.0f         // 9.5 sigma of bf16-coarse error (R5/R6 validated at 4.0)
#define CHUNK_CAP 2048       // rows per chunk list (mean ~73)

typedef unsigned int u32;
typedef unsigned long long u64;
typedef unsigned short u16;
typedef __attribute__((ext_vector_type(8))) short short8;   // 8 bf16 = 4 VGPRs
typedef __attribute__((ext_vector_type(4))) float f32x4;

__device__ __forceinline__ u32 float_to_ordered(float f) {
    u32 u = __float_as_uint(f);
    return (u & 0x80000000u) ? ~u : (u | 0x80000000u);
}

__device__ __forceinline__ u16 bf16_rne(float x) {
    u32 u = __float_as_uint(x);
    u32 r = u + 0x7FFFu + ((u >> 16) & 1u);
    return (u16)(r >> 16);
}

__device__ __forceinline__ void gl_lds16(const void* g, void* l) {
    __builtin_amdgcn_global_load_lds((const __attribute__((address_space(1))) u32*)g,
                                     (__attribute__((address_space(3))) u32*)l,
                                     16, 0, 0);
}

__device__ __forceinline__ u64 umin64(u64 a, u64 b) { return a < b ? a : b; }

// ---------------------------------------------------------------------------
// Kernel 1: prep. Blocks [0,16384): z -> z_hi bf16 + init packed/chunk_count.
// Blocks [16384,18432): emb -> e_hi bf16 + ||e||^2 (one wave per code).
// ---------------------------------------------------------------------------
__global__ __launch_bounds__(256) void vq_prep(
    const float4* __restrict__ z4, ushort4* __restrict__ zh,
    const float* __restrict__ emb, ushort4* __restrict__ eh,
    float* __restrict__ e_norms, u64* __restrict__ packed,
    u32* __restrict__ chunk_count) {
    int b = blockIdx.x;
    if (b < (M_ROWS * DDIM) / 1024) {
        int i = b * 256 + threadIdx.x;
        float4 v = z4[i];
        ushort4 h;
        h.x = bf16_rne(v.x); h.y = bf16_rne(v.y);
        h.z = bf16_rne(v.z); h.w = bf16_rne(v.w);
        zh[i] = h;
        if (i < M_ROWS) packed[i] = 0xFFFFFFFFFFFFFFFFull;
        if (i < NCHUNK) chunk_count[i] = 0u;
    } else {
        int wave = threadIdx.x >> 6;
        int lane = threadIdx.x & 63;
        int code = (b - (M_ROWS * DDIM) / 1024) * 4 + wave;
        const float4* ep = (const float4*)(emb + (size_t)code * DDIM);
        size_t base4 = (size_t)code * (DDIM / 4);
        float s = 0.f;
        #pragma unroll
        for (int j = 0; j < 2; ++j) {
            int c = lane + 64 * j;
            float4 e = ep[c];
            s += e.x * e.x + e.y * e.y + e.z * e.z + e.w * e.w;
            ushort4 h;
            h.x = bf16_rne(e.x); h.y = bf16_rne(e.y);
            h.z = bf16_rne(e.z); h.w = bf16_rne(e.w);
            eh[base4 + c] = h;
        }
        #pragma unroll
        for (int off = 32; off; off >>= 1) s += __shfl_down(s, off, 64);
        if (lane == 0) e_norms[code] = s;
    }
}

// ---------------------------------------------------------------------------
// Kernel 2: phase-1 coarse GEMM (bf16 hi*hi) + per-(row, 32-col-chunk) minima.
// R2-verified structure: 128x128 tile, BK=32, 4 waves 2x2, 4x4 frags of
// 16x16x32. Unchanged from R6.
// ---------------------------------------------------------------------------
__global__ __launch_bounds__(256) void vq_phase1(
    const u16* __restrict__ z_hi, const u16* __restrict__ e_hi,
    const float* __restrict__ e_norms,
    float* __restrict__ chunkmin) {
    __shared__ __align__(16) u16 ldsA[128][32];   // 8 KB
    __shared__ __align__(16) u16 ldsB[128][32];   // 8 KB

    const int tid  = threadIdx.x;
    const int wave = tid >> 6;
    const int lane = tid & 63;
    const int wm   = wave & 1;
    const int wn   = wave >> 1;
    const int row0 = blockIdx.x * 128;
    const int col0 = blockIdx.y * 128;

    const int srow = (wave << 5) + (lane >> 2);
    const int scol = (lane & 3) << 3;
    const u16* gA = z_hi + (size_t)(row0 + srow) * DDIM + scol;
    const u16* gB = e_hi + (size_t)(col0 + srow) * DDIM + scol;

    const int fm = (wm << 6) + (lane & 15);
    const int fn = (wn << 6) + (lane & 15);
    const int fk = (lane >> 4) << 3;

    f32x4 acc[4][4] = {};

    for (int it = 0; it < 16; ++it) {
        const int d0 = it << 5;
        __syncthreads();
        #pragma unroll
        for (int s = 0; s < 2; ++s) {
            const size_t go = (size_t)d0 + (size_t)s * 16 * DDIM;
            const int lr = (wave << 5) + (s << 4);
            gl_lds16(gA + go, &ldsA[lr][0]);
            gl_lds16(gB + go, &ldsB[lr][0]);
        }
        __syncthreads();

        short8 ah[4], bh[4];
        #pragma unroll
        for (int i = 0; i < 4; ++i) ah[i] = *(const short8*)&ldsA[fm + i * 16][fk];
        #pragma unroll
        for (int j = 0; j < 4; ++j) bh[j] = *(const short8*)&ldsB[fn + j * 16][fk];
        #pragma unroll
        for (int i = 0; i < 4; ++i)
            #pragma unroll
            for (int j = 0; j < 4; ++j)
                acc[i][j] = __builtin_amdgcn_mfma_f32_16x16x32_bf16(ah[i], bh[j], acc[i][j], 0, 0, 0);
    }

    const int cn = lane & 15;
    const int cg = lane >> 4;
    float en[4];
    #pragma unroll
    for (int j = 0; j < 4; ++j) en[j] = e_norms[col0 + (wn << 6) + j * 16 + cn];

    #pragma unroll
    for (int i = 0; i < 4; ++i)
        #pragma unroll
        for (int r = 0; r < 4; ++r) {
            float d0v = en[0] - 2.0f * acc[i][0][r];
            float d1v = en[1] - 2.0f * acc[i][1][r];
            float d2v = en[2] - 2.0f * acc[i][2][r];
            float d3v = en[3] - 2.0f * acc[i][3][r];
            float m01 = fminf(d0v, d1v);
            float m23 = fminf(d2v, d3v);
            #pragma unroll
            for (int off = 1; off < 16; off <<= 1) {
                m01 = fminf(m01, __shfl_xor(m01, off, 64));
                m23 = fminf(m23, __shfl_xor(m23, off, 64));
            }
            if (cn == 0) {
                int row_g = row0 + (wm << 6) + i * 16 + (cg << 2) + r;
                int cbase = row_g * NCHUNK + (blockIdx.y << 2) + (wn << 1);
                chunkmin[cbase]     = m01;
                chunkmin[cbase + 1] = m23;
            }
        }
}

// ---------------------------------------------------------------------------
// Kernel 3: candidate selection -> per-chunk row lists (chunk-major inversion).
// One wave per row; atomics spread over 256 chunk counters.
// ---------------------------------------------------------------------------
__global__ __launch_bounds__(256) void vq_candsel(
    const float* __restrict__ chunkmin,
    u32* __restrict__ chunk_count, u32* __restrict__ chunk_list) {
    const int wave = threadIdx.x >> 6;
    const int lane = threadIdx.x & 63;
    const int row  = blockIdx.x * 4 + wave;

    const float4* cm4 = (const float4*)(chunkmin + (size_t)row * NCHUNK);
    float4 v = cm4[lane];
    float m = fminf(fminf(v.x, v.y), fminf(v.z, v.w));
    #pragma unroll
    for (int off = 1; off < 64; off <<= 1) m = fminf(m, __shfl_xor(m, off, 64));
    const float thr = m + MARGIN;

    u64 msk[4];
    msk[0] = __ballot(v.x <= thr);
    msk[1] = __ballot(v.y <= thr);
    msk[2] = __ballot(v.z <= thr);
    msk[3] = __ballot(v.w <= thr);

    if (lane == 0) {
        #pragma unroll
        for (int j = 0; j < 4; ++j) {
            u64 mk = msk[j];
            while (mk) {
                int l = __ffsll((long long)mk) - 1;
                mk &= mk - 1;
                const int chunk = l * 4 + j;
                u32 pos = atomicAdd(&chunk_count[chunk], 1u);
                if (pos < CHUNK_CAP)
                    chunk_list[(size_t)chunk * CHUNK_CAP + pos] = (u32)row;
            }
        }
    }
}

// ---------------------------------------------------------------------------
// Kernel 4: phase-2 exact re-eval, chunk-major. Block = (chunk, half).
// Chunk's 32 fp32 code rows staged ONCE into 64KB LDS; each wave sweeps
// listed rows (z in registers, emb from LDS, 6-round shuffle reduce),
// one atomicMin(packed[row]) per (row,chunk).
// ---------------------------------------------------------------------------
__global__ __launch_bounds__(256) void vq_phase2(
    const float* __restrict__ z, const float* __restrict__ emb,
    const float* __restrict__ e_norms,
    const u32* __restrict__ chunk_count, const u32* __restrict__ chunk_list,
    u64* __restrict__ packed) {
    __shared__ __align__(16) float ch[32 * DDIM];   // 64 KB

    const int chunk = blockIdx.x >> 1;
    const int half  = blockIdx.x & 1;
    const int wave  = threadIdx.x >> 6;
    const int lane  = threadIdx.x & 63;
    const int cbase = chunk * 32;

    u32 cnt = chunk_count[chunk];
    if (cnt > CHUNK_CAP) cnt = CHUNK_CAP;
    if (cnt == 0) return;

    // stage chunk: 16384 floats, 256 threads x 16 float4, coalesced
    {
        const float4* src = (const float4*)(emb + (size_t)cbase * DDIM);
        #pragma unroll
        for (int it = 0; it < 16; ++it) {
            int o = it * 256 + threadIdx.x;
            *(float4*)&ch[o * 4] = src[o];
        }
    }
    __syncthreads();

    float en[32];   // uniform per block; scalar-cached
    #pragma unroll
    for (int k = 0; k < 32; ++k) en[k] = e_norms[cbase + k];

    for (u32 p = (u32)(half + 2 * wave); p < cnt; p += 8) {
        const int row = (int)chunk_list[(size_t)chunk * CHUNK_CAP + p];
        const float4* z4 = (const float4*)(z + (size_t)row * DDIM);
        float4 za = z4[2 * lane];
        float4 zb = z4[2 * lane + 1];

        float part[32];
        #pragma unroll
        for (int k = 0; k < 32; ++k) {
            const float* eb = &ch[k * DDIM + lane * 8];
            float4 ea = *(const float4*)eb;
            float4 e2 = *(const float4*)(eb + 4);
            part[k] = za.x * ea.x + za.y * ea.y + za.z * ea.z + za.w * ea.w
                    + zb.x * e2.x + zb.y * e2.y + zb.z * e2.z + zb.w * e2.w;
        }
        #pragma unroll
        for (int off = 1; off < 64; off <<= 1)
            #pragma unroll
            for (int k = 0; k < 32; ++k)
                part[k] += __shfl_xor(part[k], off, 64);

        if (lane == 0) {
            u64 best = 0xFFFFFFFFFFFFFFFFull;
            #pragma unroll
            for (int k = 0; k < 32; ++k) {
                float dist = en[k] - 2.0f * part[k];
                best = umin64(best, ((u64)float_to_ordered(dist) << 32) | (u32)(cbase + k));
            }
            atomicMin(&packed[row], best);
        }
    }
}

// ---------------------------------------------------------------------------
// Kernel 5: gather winner rows, float indices, per-block loss partial.
// ---------------------------------------------------------------------------
__global__ __launch_bounds__(256) void vq_gather_loss(
    const float* __restrict__ z, const float* __restrict__ emb,
    const u64* __restrict__ packed,
    float* __restrict__ out_q, float* __restrict__ out_idx,
    float* __restrict__ partials) {
    int wave = threadIdx.x >> 6;
    int lane = threadIdx.x & 63;
    int row  = blockIdx.x * 4 + wave;

    int idx = (int)(packed[row] & 0xFFFFFFFFull);
    const float4* qp = (const float4*)(emb + (size_t)idx * DDIM);
    const float4* zp = (const float4*)(z + (size_t)row * DDIM);
    float4*       op = (float4*)(out_q + (size_t)row * DDIM);

    float local = 0.f;
    #pragma unroll
    for (int j = 0; j < 2; ++j) {
        int c = lane + 64 * j;
        float4 qv = qp[c];
        float4 v = zp[c];
        op[c] = qv;
        float dx = v.x - qv.x, dy = v.y - qv.y, dz = v.z - qv.z, dw = v.w - qv.w;
        local += dx * dx + dy * dy + dz * dz + dw * dw;
    }
    #pragma unroll
    for (int off = 32; off; off >>= 1) local += __shfl_down(local, off, 64);

    __shared__ float wsum[4];
    if (lane == 0) { wsum[wave] = local; out_idx[row] = (float)idx; }
    __syncthreads();
    if (threadIdx.x == 0)
        partials[blockIdx.x] = wsum[0] + wsum[1] + wsum[2] + wsum[3];
}

// ---------------------------------------------------------------------------
// Kernel 6: reduce loss partials -> scalar loss.
// ---------------------------------------------------------------------------
__global__ __launch_bounds__(256) void vq_loss_reduce(
    const float* __restrict__ partials, float* __restrict__ out_loss) {
    __shared__ float red[256];
    float s = 0.f;
    for (int i = threadIdx.x; i < M_ROWS / 4; i += 256) s += partials[i];
    red[threadIdx.x] = s;
    __syncthreads();
    for (int off = 128; off; off >>= 1) {
        if (threadIdx.x < off) red[threadIdx.x] += red[threadIdx.x + off];
        __syncthreads();
    }
    if (threadIdx.x == 0)
        out_loss[0] = 0.25f * red[0] / ((float)M_ROWS * (float)DDIM);
}

extern "C" void kernel_launch(void* const* d_in, const int* in_sizes, int n_in,
                              void* d_out, int out_size, void* d_ws, size_t ws_size,
                              hipStream_t stream) {
    const float* z   = (const float*)d_in[0];   // [16384, 512]
    const float* emb = (const float*)d_in[1];   // [8192, 512]

    float* out      = (float*)d_out;
    float* out_q    = out;
    float* out_idx  = out + (size_t)M_ROWS * DDIM;
    float* out_loss = out + (size_t)M_ROWS * DDIM + M_ROWS;

    char* ws = (char*)d_ws;
    float* e_norms     = (float*)ws;                       // 32 KB
    float* partials    = (float*)(ws + 32768);             // 16 KB
    u32*   chunk_count = (u32*)(ws + 49152);               // 1 KB (pad 16K)
    u64*   packed      = (u64*)(ws + 65536);               // 128 KB
    float* chunkmin    = (float*)(ws + 196608);            // 16 MB
    u32*   chunk_list  = (u32*)(ws + 196608 + 16777216);   // 2 MB
    size_t tail        = 196608 + 16777216 + 2097152;

    const size_t zbytes = (size_t)M_ROWS * DDIM * 2;   // 16 MB
    const size_t ebytes = (size_t)N_CODES * DDIM * 2;  // 8 MB
    u16 *z_hi, *e_hi;
    if (ws_size >= tail + zbytes + ebytes) {
        z_hi = (u16*)(ws + tail);
        e_hi = (u16*)(ws + tail + zbytes);
    } else {
        // stash bf16 copies in out_q region (33.5 MB >= 24 MB); phase2/gather
        // rewrite out_q only after phase1 consumed them (stream-ordered).
        z_hi = (u16*)out_q;
        e_hi = (u16*)((char*)out_q + zbytes);
    }

    const int zblocks = (M_ROWS * DDIM) / 1024;      // 16384
    const int eblocks = N_CODES / 4;                 // 2048
    vq_prep<<<zblocks + eblocks, 256, 0, stream>>>(
        (const float4*)z, (ushort4*)z_hi, emb, (ushort4*)e_hi,
        e_norms, packed, chunk_count);

    vq_phase1<<<dim3(M_ROWS / 128, N_CODES / 128), 256, 0, stream>>>(
        z_hi, e_hi, e_norms, chunkmin);

    vq_candsel<<<M_ROWS / 4, 256, 0, stream>>>(chunkmin, chunk_count, chunk_list);

    vq_phase2<<<NCHUNK * 2, 256, 0, stream>>>(
        z, emb, e_norms, chunk_count, chunk_list, packed);

    vq_gather_loss<<<M_ROWS / 4, 256, 0, stream>>>(
        z, emb, packed, out_q, out_idx, partials);

    vq_loss_reduce<<<1, 256, 0, stream>>>(partials, out_loss);
}